// Round 1
// baseline (177.322 us; speedup 1.0000x reference)
//
#include <hip/hip_runtime.h>
#include <math.h>

#define NROWS 2048
#define HDIM 768
#define DDIM 128
#define FEAT 512
#define NJS 8      // j-slices
#define TI 64
#define TJS 256
#define KC 32

// Online logsumexp-style merge: state (m, n, d) <- merge with (m2, n2, d2).
__device__ __forceinline__ void mergeState(float& m, float& n, float& d,
                                           float m2, float n2, float d2) {
  float M = fmaxf(m, m2);
  float s1 = (m >= M) ? 1.0f : __expf(m - M);   // m==-inf & M==-inf -> s1=1, n=0 anyway
  float s2 = (m2 >= M) ? 1.0f : __expf(m2 - M);
  n = n * s1 + n2 * s2;
  d = d * s1 + d2 * s2;
  m = M;
}

// ---------------------------------------------------------------------------
// K1: h = relu(E); mu = h@Wmu + bmu; sigma = elu(h@Wsg + bsg) + 1 + 1e-14.
// Emit per-row feature vector FA[r][512] = [1/s | s+mu^2 | -2*mu/s | mu]
// and q[r] = sum_d mu^2/s.
// Block: 8 rows, 256 threads. thread = 2 rows x 4 cols of one matrix.
// ---------------------------------------------------------------------------
__global__ __launch_bounds__(256) void k1_project(
    const float* __restrict__ E,
    const float* __restrict__ Wmu, const float* __restrict__ bmu,
    const float* __restrict__ Wsg, const float* __restrict__ bsg,
    float* __restrict__ FA, float* __restrict__ qout)
{
  __shared__ float hsm[8][HDIM];     // 24 KB
  __shared__ float sig[8][DDIM];     // 4 KB
  const int t = threadIdx.x;
  const int r0 = blockIdx.x * 8;

  // stage relu(E) rows: 8*768 floats = 1536 float4
  const float4* src = reinterpret_cast<const float4*>(E + (size_t)r0 * HDIM);
  float4* dst = reinterpret_cast<float4*>(&hsm[0][0]);
  #pragma unroll
  for (int f = 0; f < 6; ++f) {
    float4 v = src[t + 256 * f];
    v.x = fmaxf(v.x, 0.f); v.y = fmaxf(v.y, 0.f);
    v.z = fmaxf(v.z, 0.f); v.w = fmaxf(v.w, 0.f);
    dst[t + 256 * f] = v;
  }
  __syncthreads();

  const int cg  = t & 63;        // lane id == col group
  const int rh  = t >> 6;        // wave id 0..3
  const int c4  = cg * 4;        // 0..252 over [mu cols | sigma cols]
  const int mat = c4 >> 7;       // 0 = mu, 1 = sigma
  const int col = c4 & 127;
  const float* W = mat ? Wsg : Wmu;
  const int ra = rh * 2, rb = ra + 1;

  float acc[2][4] = {{0.f,0.f,0.f,0.f},{0.f,0.f,0.f,0.f}};
  #pragma unroll 2
  for (int k4 = 0; k4 < HDIM; k4 += 4) {
    float4 ha = *reinterpret_cast<const float4*>(&hsm[ra][k4]);
    float4 hb = *reinterpret_cast<const float4*>(&hsm[rb][k4]);
    const float hav[4] = {ha.x, ha.y, ha.z, ha.w};
    const float hbv[4] = {hb.x, hb.y, hb.z, hb.w};
    #pragma unroll
    for (int kk = 0; kk < 4; ++kk) {
      float4 w = *reinterpret_cast<const float4*>(&W[(size_t)(k4 + kk) * DDIM + col]);
      acc[0][0] = fmaf(hav[kk], w.x, acc[0][0]);
      acc[0][1] = fmaf(hav[kk], w.y, acc[0][1]);
      acc[0][2] = fmaf(hav[kk], w.z, acc[0][2]);
      acc[0][3] = fmaf(hav[kk], w.w, acc[0][3]);
      acc[1][0] = fmaf(hbv[kk], w.x, acc[1][0]);
      acc[1][1] = fmaf(hbv[kk], w.y, acc[1][1]);
      acc[1][2] = fmaf(hbv[kk], w.z, acc[1][2]);
      acc[1][3] = fmaf(hbv[kk], w.w, acc[1][3]);
    }
  }

  if (mat == 1) {
    #pragma unroll
    for (int rr = 0; rr < 2; ++rr) {
      const int r = ra + rr;
      #pragma unroll
      for (int c = 0; c < 4; ++c) {
        float z = acc[rr][c] + bsg[col + c];
        float s = (z > 0.f ? z + 1.0f : __expf(z)) + 1e-14f;
        sig[r][col + c] = s;
      }
    }
  }
  __syncthreads();

  float qp[2] = {0.f, 0.f};
  if (mat == 0) {
    #pragma unroll
    for (int rr = 0; rr < 2; ++rr) {
      const int r = ra + rr;
      float4 sv = *reinterpret_cast<const float4*>(&sig[r][col]);
      const float svv[4] = {sv.x, sv.y, sv.z, sv.w};
      float f1[4], f2[4], f3[4], f4[4];
      #pragma unroll
      for (int c = 0; c < 4; ++c) {
        float mu  = acc[rr][c] + bmu[col + c];
        float s   = svv[c];
        float inv = 1.0f / s;
        f1[c] = inv;
        f2[c] = s + mu * mu;
        f3[c] = -2.0f * mu * inv;
        f4[c] = mu;
        qp[rr] += mu * mu * inv;
      }
      float* row = FA + (size_t)(r0 + r) * FEAT;
      *reinterpret_cast<float4*>(&row[      col]) = make_float4(f1[0], f1[1], f1[2], f1[3]);
      *reinterpret_cast<float4*>(&row[128 + col]) = make_float4(f2[0], f2[1], f2[2], f2[3]);
      *reinterpret_cast<float4*>(&row[256 + col]) = make_float4(f3[0], f3[1], f3[2], f3[3]);
      *reinterpret_cast<float4*>(&row[384 + col]) = make_float4(f4[0], f4[1], f4[2], f4[3]);
    }
  }
  // reduce q over the 32 mu-lanes of each wave (lanes 0..31)
  #pragma unroll
  for (int o = 16; o; o >>= 1) {
    qp[0] += __shfl_xor(qp[0], o, 32);
    qp[1] += __shfl_xor(qp[1], o, 32);
  }
  if (cg == 0) {
    qout[r0 + ra] = qp[0];
    qout[r0 + rb] = qp[1];
  }
}

// ---------------------------------------------------------------------------
// K2: all-pairs. Block = 64 i-rows x 256 j-cols; thread = 8x8 microtile.
// Phase A: exact-equality scan over mu (128 dims) -> 64-bit alive mask.
// Phase B: 512-dim fp32 dot via LDS tiles (B side reads FA[j][k^128]).
// Phase C: per-row online (max-shifted) num/den/cnt; lane-combine; write
//          per-(jslice,row) partial float4(m,num,den,cnt).
// ---------------------------------------------------------------------------
__global__ __launch_bounds__(256) void k2_pairs(
    const float* __restrict__ FA, const float* __restrict__ qv,
    const int* __restrict__ labels, const int* __restrict__ msk,
    float4* __restrict__ partials)
{
  __shared__ float As[KC][TI];    // 8 KB
  __shared__ float Bs[KC][TJS];   // 32 KB
  const int t  = threadIdx.x;
  const int tx = t & 31, ty = t >> 5;
  const int i0 = blockIdx.x * TI;
  const int j0 = blockIdx.y * TJS;

  auto loadTiles = [&](int ka, int kb) {
    #pragma unroll
    for (int rep = 0; rep < 2; ++rep) {
      int f = t + rep * 256;
      int ri = f >> 3, kq = f & 7;
      float4 v = *reinterpret_cast<const float4*>(&FA[(size_t)(i0 + ri) * FEAT + ka + kq * 4]);
      As[kq * 4 + 0][ri] = v.x; As[kq * 4 + 1][ri] = v.y;
      As[kq * 4 + 2][ri] = v.z; As[kq * 4 + 3][ri] = v.w;
    }
    #pragma unroll
    for (int rep = 0; rep < 8; ++rep) {
      int f = t + rep * 256;
      int rj = f >> 3, kq = f & 7;
      float4 v = *reinterpret_cast<const float4*>(&FA[(size_t)(j0 + rj) * FEAT + kb + kq * 4]);
      Bs[kq * 4 + 0][rj] = v.x; Bs[kq * 4 + 1][rj] = v.y;
      Bs[kq * 4 + 2][rj] = v.z; Bs[kq * 4 + 3][rj] = v.w;
    }
  };

  // ---- Phase A: equality scan over mu (feature block 3: offset 384) ----
  unsigned long long alive;
  {
    float mn[8][8];
    #pragma unroll
    for (int a = 0; a < 8; ++a)
      #pragma unroll
      for (int b = 0; b < 8; ++b) mn[a][b] = 1e30f;
    for (int kc = 0; kc < 4; ++kc) {
      __syncthreads();
      loadTiles(384 + kc * KC, 384 + kc * KC);
      __syncthreads();
      #pragma unroll 8
      for (int k = 0; k < KC; ++k) {
        float av[8], bv[8];
        *reinterpret_cast<float4*>(&av[0]) = *reinterpret_cast<const float4*>(&As[k][ty * 8]);
        *reinterpret_cast<float4*>(&av[4]) = *reinterpret_cast<const float4*>(&As[k][ty * 8 + 4]);
        *reinterpret_cast<float4*>(&bv[0]) = *reinterpret_cast<const float4*>(&Bs[k][tx * 8]);
        *reinterpret_cast<float4*>(&bv[4]) = *reinterpret_cast<const float4*>(&Bs[k][tx * 8 + 4]);
        #pragma unroll
        for (int a = 0; a < 8; ++a)
          #pragma unroll
          for (int b = 0; b < 8; ++b)
            mn[a][b] = fminf(mn[a][b], fabsf(av[a] - bv[b]));
      }
    }
    alive = 0ull;
    #pragma unroll
    for (int a = 0; a < 8; ++a)
      #pragma unroll
      for (int b = 0; b < 8; ++b)
        if (mn[a][b] != 0.0f) alive |= (1ull << (a * 8 + b));
  }

  // ---- Phase B: the 512-dim dot ----
  float acc[8][8];
  #pragma unroll
  for (int a = 0; a < 8; ++a)
    #pragma unroll
    for (int b = 0; b < 8; ++b) acc[a][b] = 0.f;

  for (int kc = 0; kc < 16; ++kc) {
    __syncthreads();
    loadTiles(kc * KC, (kc * KC) ^ 128);
    __syncthreads();
    #pragma unroll 8
    for (int k = 0; k < KC; ++k) {
      float av[8], bv[8];
      *reinterpret_cast<float4*>(&av[0]) = *reinterpret_cast<const float4*>(&As[k][ty * 8]);
      *reinterpret_cast<float4*>(&av[4]) = *reinterpret_cast<const float4*>(&As[k][ty * 8 + 4]);
      *reinterpret_cast<float4*>(&bv[0]) = *reinterpret_cast<const float4*>(&Bs[k][tx * 8]);
      *reinterpret_cast<float4*>(&bv[4]) = *reinterpret_cast<const float4*>(&Bs[k][tx * 8 + 4]);
      #pragma unroll
      for (int a = 0; a < 8; ++a)
        #pragma unroll
        for (int b = 0; b < 8; ++b)
          acc[a][b] = fmaf(av[a], bv[b], acc[a][b]);
    }
  }

  // ---- Phase C: fold into per-row online state ----
  float qj[8]; int lj[8]; float vj[8];
  #pragma unroll
  for (int b = 0; b < 8; ++b) {
    const int j = j0 + tx * 8 + b;
    qj[b] = qv[j];
    lj[b] = labels[j];
    vj[b] = (msk[j] == 1 && lj[b] >= 0) ? 1.f : 0.f;
  }
  float rm[8], rn[8], rd[8], rc[8];
  #pragma unroll
  for (int a = 0; a < 8; ++a) { rm[a] = -INFINITY; rn[a] = 0.f; rd[a] = 0.f; rc[a] = 0.f; }

  #pragma unroll
  for (int a = 0; a < 8; ++a) {
    const int i = i0 + ty * 8 + a;
    const float qi = qv[i];
    const int li = labels[i];
    const bool vi = (msk[i] == 1 && li >= 0);
    if (vi) {
      #pragma unroll
      for (int b = 0; b < 8; ++b) {
        const bool inc = (vj[b] != 0.f) && ((alive >> (a * 8 + b)) & 1ull);
        if (inc) {
          float l = 64.0f - 0.25f * (qi + qj[b] + acc[a][b]);
          float w = (li == lj[b]) ? 1.0f : 0.0f;
          mergeState(rm[a], rn[a], rd[a], l, w, 1.0f);
          rc[a] += w;
        }
      }
    }
  }

  // combine across the 32 tx-lanes (each half-wave shares the same 8 rows)
  #pragma unroll
  for (int o = 16; o; o >>= 1) {
    #pragma unroll
    for (int a = 0; a < 8; ++a) {
      float m2 = __shfl_xor(rm[a], o, 32);
      float n2 = __shfl_xor(rn[a], o, 32);
      float d2 = __shfl_xor(rd[a], o, 32);
      float c2 = __shfl_xor(rc[a], o, 32);
      mergeState(rm[a], rn[a], rd[a], m2, n2, d2);
      rc[a] += c2;
    }
  }
  if (tx == 0) {
    #pragma unroll
    for (int a = 0; a < 8; ++a)
      partials[(size_t)blockIdx.y * NROWS + i0 + ty * 8 + a] =
          make_float4(rm[a], rn[a], rd[a], rc[a]);
  }
}

// ---------------------------------------------------------------------------
// K3: merge j-slice partials per row, compute lf for sel rows, reduce scalar.
// Single block of 256 threads.
// ---------------------------------------------------------------------------
__global__ __launch_bounds__(256) void k3_final(const float4* __restrict__ partials,
                                               float* __restrict__ out)
{
  const int t = threadIdx.x;
  float lfsum = 0.f, ns = 0.f;
  for (int r = t; r < NROWS; r += 256) {
    float m = -INFINITY, n = 0.f, d = 0.f, c = 0.f;
    #pragma unroll
    for (int js = 0; js < NJS; ++js) {
      float4 p = partials[(size_t)js * NROWS + r];
      mergeState(m, n, d, p.x, p.y, p.z);
      c += p.w;
    }
    if (c > 0.f) {
      lfsum += log2f(d) - log2f(n) + log2f(c);   // shift m cancels between den & num
      ns += 1.f;
    }
  }
  #pragma unroll
  for (int o = 32; o; o >>= 1) {
    lfsum += __shfl_down(lfsum, o);
    ns    += __shfl_down(ns, o);
  }
  __shared__ float sl[4], sn[4];
  if ((t & 63) == 0) { sl[t >> 6] = lfsum; sn[t >> 6] = ns; }
  __syncthreads();
  if (t == 0) {
    float L = sl[0] + sl[1] + sl[2] + sl[3];
    float C = sn[0] + sn[1] + sn[2] + sn[3];
    out[0] = L / fmaxf(C, 1.0f);
  }
}

// ---------------------------------------------------------------------------
extern "C" void kernel_launch(void* const* d_in, const int* in_sizes, int n_in,
                              void* d_out, int out_size, void* d_ws, size_t ws_size,
                              hipStream_t stream) {
  const float* E   = (const float*)d_in[0];
  const int*   tid = (const int*)d_in[1];
  const int*   msk = (const int*)d_in[2];
  const float* Wmu = (const float*)d_in[3];
  const float* bmu = (const float*)d_in[4];
  const float* Wsg = (const float*)d_in[5];
  const float* bsg = (const float*)d_in[6];

  float*  FA       = (float*)d_ws;                      // [2048][512]  4 MB
  float*  qv       = FA + (size_t)NROWS * FEAT;         // [2048]       8 KB
  float4* partials = (float4*)(qv + NROWS);             // [8][2048]    128 KB

  hipLaunchKernelGGL(k1_project, dim3(NROWS / 8), dim3(256), 0, stream,
                     E, Wmu, bmu, Wsg, bsg, FA, qv);
  hipLaunchKernelGGL(k2_pairs, dim3(NROWS / TI, NJS), dim3(256), 0, stream,
                     FA, qv, tid, msk, partials);
  hipLaunchKernelGGL(k3_final, dim3(1), dim3(256), 0, stream,
                     partials, (float*)d_out);
}

// Round 2
// 131.522 us; speedup vs baseline: 1.3482x; 1.3482x over previous
//
#include <hip/hip_runtime.h>
#include <math.h>

#define NROWS 2048
#define HDIM 768
#define DDIM 128
#define FEAT 512
#define TSIZE (1u << 19)
#define TMASK (TSIZE - 1u)
#define DCAP 2048

typedef __attribute__((ext_vector_type(8))) short bf16x8;
typedef __attribute__((ext_vector_type(4))) float f32x4;

// Online logsumexp-style merge: state (m, n, d) <- merge with (m2, n2, d2).
__device__ __forceinline__ void mergeState(float& m, float& n, float& d,
                                           float m2, float n2, float d2) {
  float M = fmaxf(m, m2);
  float s1 = (m >= M) ? 1.0f : __expf(m - M);
  float s2 = (m2 >= M) ? 1.0f : __expf(m2 - M);
  n = n * s1 + n2 * s2;
  d = d * s1 + d2 * s2;
  m = M;
}

__device__ __forceinline__ unsigned short bfhi(float x) {
  unsigned int u = __float_as_uint(x);
  return (unsigned short)((u + 0x7fffu + ((u >> 16) & 1u)) >> 16);
}
__device__ __forceinline__ float bf2f(unsigned short h) {
  return __uint_as_float(((unsigned int)h) << 16);
}

// ---------------------------------------------------------------------------
// k_clear: zero hash table, row flags, dup counter.
// ---------------------------------------------------------------------------
__global__ __launch_bounds__(256) void k_clear(unsigned long long* __restrict__ tab,
                                               int* __restrict__ rowflag,
                                               int* __restrict__ dupcnt) {
  unsigned int i = blockIdx.x * 256u + threadIdx.x;   // grid 2048*256 == TSIZE
  tab[i] = 0ULL;
  if (i < NROWS) rowflag[i] = 0;
  if (i == 0) dupcnt[0] = 0;
}

// ---------------------------------------------------------------------------
// K1: mu/sigma projection. Emits Mu (fp32, for exact-equality hash),
// Fhi/Flo (bf16 split of features [1/s | s+mu^2 | -2mu/s | mu]), q.
// ---------------------------------------------------------------------------
__global__ __launch_bounds__(256) void k1_project(
    const float* __restrict__ E,
    const float* __restrict__ Wmu, const float* __restrict__ bmu,
    const float* __restrict__ Wsg, const float* __restrict__ bsg,
    float* __restrict__ Mu, unsigned short* __restrict__ Fhi,
    unsigned short* __restrict__ Flo, float* __restrict__ qout)
{
  __shared__ float hsm[8][HDIM];
  __shared__ float sig[8][DDIM];
  const int t = threadIdx.x;
  const int r0 = blockIdx.x * 8;

  const float4* src = reinterpret_cast<const float4*>(E + (size_t)r0 * HDIM);
  float4* dst = reinterpret_cast<float4*>(&hsm[0][0]);
  #pragma unroll
  for (int f = 0; f < 6; ++f) {
    float4 v = src[t + 256 * f];
    v.x = fmaxf(v.x, 0.f); v.y = fmaxf(v.y, 0.f);
    v.z = fmaxf(v.z, 0.f); v.w = fmaxf(v.w, 0.f);
    dst[t + 256 * f] = v;
  }
  __syncthreads();

  const int cg  = t & 63;
  const int rh  = t >> 6;
  const int c4  = cg * 4;
  const int mat = c4 >> 7;       // 0 = mu, 1 = sigma
  const int col = c4 & 127;
  const float* W = mat ? Wsg : Wmu;
  const int ra = rh * 2, rb = ra + 1;

  float acc[2][4] = {{0.f,0.f,0.f,0.f},{0.f,0.f,0.f,0.f}};
  #pragma unroll 2
  for (int k4 = 0; k4 < HDIM; k4 += 4) {
    float4 ha = *reinterpret_cast<const float4*>(&hsm[ra][k4]);
    float4 hb = *reinterpret_cast<const float4*>(&hsm[rb][k4]);
    const float hav[4] = {ha.x, ha.y, ha.z, ha.w};
    const float hbv[4] = {hb.x, hb.y, hb.z, hb.w};
    #pragma unroll
    for (int kk = 0; kk < 4; ++kk) {
      float4 w = *reinterpret_cast<const float4*>(&W[(size_t)(k4 + kk) * DDIM + col]);
      acc[0][0] = fmaf(hav[kk], w.x, acc[0][0]);
      acc[0][1] = fmaf(hav[kk], w.y, acc[0][1]);
      acc[0][2] = fmaf(hav[kk], w.z, acc[0][2]);
      acc[0][3] = fmaf(hav[kk], w.w, acc[0][3]);
      acc[1][0] = fmaf(hbv[kk], w.x, acc[1][0]);
      acc[1][1] = fmaf(hbv[kk], w.y, acc[1][1]);
      acc[1][2] = fmaf(hbv[kk], w.z, acc[1][2]);
      acc[1][3] = fmaf(hbv[kk], w.w, acc[1][3]);
    }
  }

  if (mat == 1) {
    #pragma unroll
    for (int rr = 0; rr < 2; ++rr) {
      const int r = ra + rr;
      #pragma unroll
      for (int c = 0; c < 4; ++c) {
        float z = acc[rr][c] + bsg[col + c];
        float s = (z > 0.f ? z + 1.0f : __expf(z)) + 1e-14f;
        sig[r][col + c] = s;
      }
    }
  }
  __syncthreads();

  float qp[2] = {0.f, 0.f};
  if (mat == 0) {
    #pragma unroll
    for (int rr = 0; rr < 2; ++rr) {
      const int r = ra + rr;
      const int row = r0 + r;
      float4 sv = *reinterpret_cast<const float4*>(&sig[r][col]);
      const float svv[4] = {sv.x, sv.y, sv.z, sv.w};
      float f1[4], f2[4], f3[4], f4[4];
      #pragma unroll
      for (int c = 0; c < 4; ++c) {
        float mu  = acc[rr][c] + bmu[col + c];
        float s   = svv[c];
        float inv = 1.0f / s;
        f1[c] = inv;
        f2[c] = s + mu * mu;
        f3[c] = -2.0f * mu * inv;
        f4[c] = mu;
        qp[rr] += mu * mu * inv;
      }
      *reinterpret_cast<float4*>(&Mu[(size_t)row * DDIM + col]) =
          make_float4(f4[0], f4[1], f4[2], f4[3]);
      const float* blocks[4] = {f1, f2, f3, f4};
      #pragma unroll
      for (int b = 0; b < 4; ++b) {
        const float* v = blocks[b];
        unsigned short h[4], l[4];
        #pragma unroll
        for (int c = 0; c < 4; ++c) {
          h[c] = bfhi(v[c]);
          l[c] = bfhi(v[c] - bf2f(h[c]));
        }
        size_t off = (size_t)row * FEAT + b * 128 + col;
        *reinterpret_cast<ushort4*>(&Fhi[off]) = make_ushort4(h[0], h[1], h[2], h[3]);
        *reinterpret_cast<ushort4*>(&Flo[off]) = make_ushort4(l[0], l[1], l[2], l[3]);
      }
    }
  }
  #pragma unroll
  for (int o = 16; o; o >>= 1) {
    qp[0] += __shfl_xor(qp[0], o, 32);
    qp[1] += __shfl_xor(qp[1], o, 32);
  }
  if (cg == 0) {
    qout[r0 + ra] = qp[0];
    qout[r0 + rb] = qp[1];
  }
}

// ---------------------------------------------------------------------------
// k_hash: exact per-dimension duplicate detection over Mu (fp32 bits).
// One thread per (row, dim). Linear-probe insert; on key match, record pair.
// ---------------------------------------------------------------------------
__global__ __launch_bounds__(256) void k_hash(const float* __restrict__ Mu,
                                              unsigned long long* __restrict__ tab,
                                              int* __restrict__ rowflag,
                                              int* __restrict__ dupcnt,
                                              int2* __restrict__ duplist) {
  int idx = blockIdx.x * 256 + threadIdx.x;     // 0..262143
  int r = idx >> 7, d = idx & 127;
  unsigned int bits = __float_as_uint(Mu[idx]);
  if (bits == 0x80000000u) bits = 0u;           // canonicalize -0.0 == +0.0
  unsigned int h = (bits * 2654435761u) ^ ((unsigned int)d * 2246822519u);
  h ^= h >> 15; h &= TMASK;
  unsigned long long me = ((unsigned long long)bits << 32) |
                          ((unsigned long long)d << 12) |
                          (unsigned long long)(r + 1);
  for (;;) {
    unsigned long long old = atomicCAS(&tab[h], 0ULL, me);
    if (old == 0ULL) break;
    if ((unsigned int)(old >> 32) == bits && (int)((old >> 12) & 127u) == d) {
      int r2 = (int)(old & 0xFFFu) - 1;
      rowflag[r] = 1; rowflag[r2] = 1;
      int e = atomicAdd(dupcnt, 1);
      if (e < DCAP) duplist[e] = make_int2(min(r, r2), max(r, r2));
    }
    h = (h + 1u) & TMASK;
  }
}

// ---------------------------------------------------------------------------
// K2: split-bf16 MFMA all-pairs GEMM (virtual K = 1536) + NT-Xent epilogue.
// Block 128x128, 4 waves (2x2), wave tile 64x64 = 4x4 frags of 16x16x32.
// LDS tiles [128][64] bf16, XOR-swizzled (16B block c ^= row&7).
// ---------------------------------------------------------------------------
__device__ __forceinline__ bf16x8 loadFrag(const unsigned short* tile, int row, int cblk) {
  int idx = row * 64 + (((cblk ^ (row & 7)) << 3));
  return *reinterpret_cast<const bf16x8*>(&tile[idx]);
}

__global__ __launch_bounds__(256) void k2_mfma(
    const unsigned short* __restrict__ Fhi, const unsigned short* __restrict__ Flo,
    const float* __restrict__ qv, const int* __restrict__ labels,
    const int* __restrict__ msk, const int* __restrict__ rowflag,
    const int* __restrict__ dupcnt, const int2* __restrict__ duplist,
    float4* __restrict__ partials)
{
  __shared__ unsigned short At[128 * 64];   // 16 KB
  __shared__ unsigned short Bt[128 * 64];   // 16 KB
  __shared__ float qiL[128], qjL[128];
  __shared__ int livL[128], ljvL[128], fliL[128], fljL[128];

  const int t = threadIdx.x;
  const int bi = blockIdx.x, bj = blockIdx.y;
  const int i0 = bi * 128, j0 = bj * 128;

  if (t < 128) {
    int i = i0 + t;
    qiL[t] = qv[i];
    livL[t] = (msk[i] == 1 && labels[i] >= 0) ? labels[i] : -1;
    fliL[t] = rowflag[i];
  } else {
    int j = j0 + (t - 128);
    qjL[t - 128] = qv[j];
    ljvL[t - 128] = (msk[j] == 1 && labels[j] >= 0) ? labels[j] : -1;
    fljL[t - 128] = rowflag[j];
  }

  // staging constants: 4 reps of 256 threads cover 1024 x 16B per tile
  int sidx[4]; size_t aoff[4], boff[4];
  #pragma unroll
  for (int rep = 0; rep < 4; ++rep) {
    int f = t + rep * 256;
    int row = f >> 3, c = f & 7;
    sidx[rep] = row * 64 + ((c ^ (row & 7)) << 3);
    aoff[rep] = (size_t)(i0 + row) * FEAT + c * 8;
    boff[rep] = (size_t)(j0 + row) * FEAT + c * 8;
  }

  f32x4 acc[16];
  #pragma unroll
  for (int x = 0; x < 16; ++x) { acc[x][0] = 0.f; acc[x][1] = 0.f; acc[x][2] = 0.f; acc[x][3] = 0.f; }

  const int wid = t >> 6, lane = t & 63;
  const int wr = wid >> 1, wc = wid & 1;
  const int gq = lane >> 4, c0 = lane & 15;

  for (int it = 0; it < 24; ++it) {
    const int term = it >> 3;               // 0: hi*hi, 1: hi*lo, 2: lo*hi
    const int kb = (it & 7) * 64;
    const unsigned short* Fa = (term == 2) ? Flo : Fhi;
    const unsigned short* Fb = (term == 1) ? Flo : Fhi;
    const int kbB = kb ^ 128;               // feature-block swap on B side
    __syncthreads();
    #pragma unroll
    for (int rep = 0; rep < 4; ++rep) {
      uint4 va = *reinterpret_cast<const uint4*>(&Fa[aoff[rep] + kb]);
      *reinterpret_cast<uint4*>(&At[sidx[rep]]) = va;
      uint4 vb = *reinterpret_cast<const uint4*>(&Fb[boff[rep] + kbB]);
      *reinterpret_cast<uint4*>(&Bt[sidx[rep]]) = vb;
    }
    __syncthreads();
    #pragma unroll
    for (int kc = 0; kc < 2; ++kc) {
      bf16x8 af[4], bfr[4];
      #pragma unroll
      for (int fa = 0; fa < 4; ++fa)
        af[fa] = loadFrag(At, wr * 64 + fa * 16 + c0, kc * 4 + gq);
      #pragma unroll
      for (int fb = 0; fb < 4; ++fb)
        bfr[fb] = loadFrag(Bt, wc * 64 + fb * 16 + c0, kc * 4 + gq);
      #pragma unroll
      for (int fa = 0; fa < 4; ++fa)
        #pragma unroll
        for (int fb = 0; fb < 4; ++fb)
          acc[fa * 4 + fb] = __builtin_amdgcn_mfma_f32_16x16x32_bf16(
              af[fa], bfr[fb], acc[fa * 4 + fb], 0, 0, 0);
    }
  }

  // ---- epilogue: NT-Xent online merge per output row ----
  const int ndup = min(*dupcnt, DCAP);
  #pragma unroll
  for (int fa = 0; fa < 4; ++fa) {
    #pragma unroll
    for (int r = 0; r < 4; ++r) {
      const int iloc = wr * 64 + fa * 16 + gq * 4 + r;   // D row (m89 mapping)
      const int gi = i0 + iloc;
      const int li = livL[iloc];
      const float qi = qiL[iloc];
      const int fi = fliL[iloc];
      float m = -INFINITY, n = 0.f, d = 0.f, c = 0.f;
      if (li >= 0) {
        #pragma unroll
        for (int fb = 0; fb < 4; ++fb) {
          const int jloc = wc * 64 + fb * 16 + c0;       // D col
          const int gj = j0 + jloc;
          const int lj = ljvL[jloc];
          bool inc = (lj >= 0) && (gi != gj);
          if (inc && fi && fljL[jloc]) {
            int plo = min(gi, gj), phi = max(gi, gj);
            for (int e = 0; e < ndup; ++e) {
              int2 p = duplist[e];
              if (p.x == plo && p.y == phi) { inc = false; break; }
            }
          }
          if (inc) {
            float S = acc[fa * 4 + fb][r];
            float l = 64.0f - 0.25f * (qi + qjL[jloc] + S);
            float w = (li == lj) ? 1.0f : 0.0f;
            mergeState(m, n, d, l, w, 1.0f);
            c += w;
          }
        }
      }
      #pragma unroll
      for (int o = 1; o < 16; o <<= 1) {
        float m2 = __shfl_xor(m, o);
        float n2 = __shfl_xor(n, o);
        float d2 = __shfl_xor(d, o);
        float c2 = __shfl_xor(c, o);
        mergeState(m, n, d, m2, n2, d2);
        c += c2;
      }
      if (c0 == 0)
        partials[(size_t)(bj * 2 + wc) * NROWS + gi] = make_float4(m, n, d, c);
    }
  }
}

// ---------------------------------------------------------------------------
// K3a: merge 32 j-slices per row, per-block partial sums (no atomics).
// ---------------------------------------------------------------------------
__global__ __launch_bounds__(256) void k3a(const float4* __restrict__ partials,
                                           float2* __restrict__ bsums)
{
  const int r = blockIdx.x * 256 + threadIdx.x;
  float m = -INFINITY, n = 0.f, d = 0.f, c = 0.f;
  #pragma unroll
  for (int js = 0; js < 32; ++js) {
    float4 p = partials[(size_t)js * NROWS + r];
    mergeState(m, n, d, p.x, p.y, p.z);
    c += p.w;
  }
  float lf = 0.f, ns = 0.f;
  if (c > 0.f) {
    lf = log2f(d) - log2f(n) + log2f(c);
    ns = 1.f;
  }
  #pragma unroll
  for (int o = 32; o; o >>= 1) {
    lf += __shfl_down(lf, o);
    ns += __shfl_down(ns, o);
  }
  __shared__ float sl[4], sn[4];
  const int wid = threadIdx.x >> 6;
  if ((threadIdx.x & 63) == 0) { sl[wid] = lf; sn[wid] = ns; }
  __syncthreads();
  if (threadIdx.x == 0)
    bsums[blockIdx.x] = make_float2(sl[0] + sl[1] + sl[2] + sl[3],
                                    sn[0] + sn[1] + sn[2] + sn[3]);
}

__global__ __launch_bounds__(64) void k3b(const float2* __restrict__ bsums,
                                          float* __restrict__ out)
{
  if (threadIdx.x == 0) {
    float L = 0.f, C = 0.f;
    for (int b = 0; b < 8; ++b) { L += bsums[b].x; C += bsums[b].y; }
    out[0] = L / fmaxf(C, 1.0f);
  }
}

// ---------------------------------------------------------------------------
extern "C" void kernel_launch(void* const* d_in, const int* in_sizes, int n_in,
                              void* d_out, int out_size, void* d_ws, size_t ws_size,
                              hipStream_t stream) {
  const float* E   = (const float*)d_in[0];
  const int*   tid = (const int*)d_in[1];
  const int*   msk = (const int*)d_in[2];
  const float* Wmu = (const float*)d_in[3];
  const float* bmu = (const float*)d_in[4];
  const float* Wsg = (const float*)d_in[5];
  const float* bsg = (const float*)d_in[6];

  unsigned char* w = (unsigned char*)d_ws;
  unsigned short* Fhi = (unsigned short*)w;            w += (size_t)NROWS * FEAT * 2;  // 2 MB
  unsigned short* Flo = (unsigned short*)w;            w += (size_t)NROWS * FEAT * 2;  // 2 MB
  float* Mu           = (float*)w;                     w += (size_t)NROWS * DDIM * 4;  // 1 MB
  float* qv           = (float*)w;                     w += (size_t)NROWS * 4;
  unsigned long long* tab = (unsigned long long*)w;    w += (size_t)TSIZE * 8;         // 4 MB
  int* rowflag        = (int*)w;                       w += (size_t)NROWS * 4;
  int* dupcnt         = (int*)w;                       w += 256;
  float2* bsums       = (float2*)w;                    w += 256;
  int2* duplist       = (int2*)w;                      w += (size_t)DCAP * 8;
  float4* partials    = (float4*)w;                    w += (size_t)32 * NROWS * 16;   // 1 MB

  k_clear<<<TSIZE / 256, 256, 0, stream>>>(tab, rowflag, dupcnt);
  k1_project<<<NROWS / 8, 256, 0, stream>>>(E, Wmu, bmu, Wsg, bsg, Mu, Fhi, Flo, qv);
  k_hash<<<(NROWS * DDIM) / 256, 256, 0, stream>>>(Mu, tab, rowflag, dupcnt, duplist);
  k2_mfma<<<dim3(16, 16), 256, 0, stream>>>(Fhi, Flo, qv, tid, msk, rowflag,
                                            dupcnt, duplist, partials);
  k3a<<<8, 256, 0, stream>>>(partials, bsums);
  k3b<<<1, 64, 0, stream>>>(bsums, (float*)d_out);
}

// Round 3
// 87.481 us; speedup vs baseline: 2.0270x; 1.5034x over previous
//
#include <hip/hip_runtime.h>
#include <math.h>

#define NROWS 2048
#define HDIM 768
#define DDIM 128
#define FEAT 512
#define DCAP 2048

typedef __attribute__((ext_vector_type(8))) short bf16x8;
typedef __attribute__((ext_vector_type(4))) float f32x4;

// Online logsumexp-style merge: state (m, n, d) <- merge with (m2, n2, d2).
__device__ __forceinline__ void mergeState(float& m, float& n, float& d,
                                           float m2, float n2, float d2) {
  float M = fmaxf(m, m2);
  float s1 = (m >= M) ? 1.0f : __expf(m - M);
  float s2 = (m2 >= M) ? 1.0f : __expf(m2 - M);
  n = n * s1 + n2 * s2;
  d = d * s1 + d2 * s2;
  m = M;
}

__device__ __forceinline__ unsigned short bfhi(float x) {
  unsigned int u = __float_as_uint(x);
  return (unsigned short)((u + 0x7fffu + ((u >> 16) & 1u)) >> 16);
}
__device__ __forceinline__ float bf2f(unsigned short h) {
  return __uint_as_float(((unsigned int)h) << 16);
}

__device__ __forceinline__ void gload16(const void* g, void* l) {
  __builtin_amdgcn_global_load_lds(
      (const __attribute__((address_space(1))) void*)g,
      (__attribute__((address_space(3))) void*)l, 16, 0, 0);
}

// ---------------------------------------------------------------------------
// K1: mu/sigma projection. Emits Mu (fp32, for exact-equality hash),
// Fhi/Flo (bf16 split of features [1/s | s+mu^2 | -2mu/s | mu]), q.
// Also clears rowflag/dupcnt (used by later kernels).
// ---------------------------------------------------------------------------
__global__ __launch_bounds__(256) void k1_project(
    const float* __restrict__ E,
    const float* __restrict__ Wmu, const float* __restrict__ bmu,
    const float* __restrict__ Wsg, const float* __restrict__ bsg,
    float* __restrict__ Mu, unsigned short* __restrict__ Fhi,
    unsigned short* __restrict__ Flo, float* __restrict__ qout,
    int* __restrict__ rowflag, int* __restrict__ dupcnt)
{
  __shared__ float hsm[8][HDIM];
  __shared__ float sig[8][DDIM];
  const int t = threadIdx.x;
  const int r0 = blockIdx.x * 8;

  if (blockIdx.x < 8) rowflag[blockIdx.x * 256 + t] = 0;
  if (blockIdx.x == 8 && t == 0) dupcnt[0] = 0;

  const float4* src = reinterpret_cast<const float4*>(E + (size_t)r0 * HDIM);
  float4* dst = reinterpret_cast<float4*>(&hsm[0][0]);
  #pragma unroll
  for (int f = 0; f < 6; ++f) {
    float4 v = src[t + 256 * f];
    v.x = fmaxf(v.x, 0.f); v.y = fmaxf(v.y, 0.f);
    v.z = fmaxf(v.z, 0.f); v.w = fmaxf(v.w, 0.f);
    dst[t + 256 * f] = v;
  }
  __syncthreads();

  const int cg  = t & 63;
  const int rh  = t >> 6;
  const int c4  = cg * 4;
  const int mat = c4 >> 7;       // 0 = mu, 1 = sigma
  const int col = c4 & 127;
  const float* W = mat ? Wsg : Wmu;
  const int ra = rh * 2, rb = ra + 1;

  float acc[2][4] = {{0.f,0.f,0.f,0.f},{0.f,0.f,0.f,0.f}};
  #pragma unroll 2
  for (int k4 = 0; k4 < HDIM; k4 += 4) {
    float4 ha = *reinterpret_cast<const float4*>(&hsm[ra][k4]);
    float4 hb = *reinterpret_cast<const float4*>(&hsm[rb][k4]);
    const float hav[4] = {ha.x, ha.y, ha.z, ha.w};
    const float hbv[4] = {hb.x, hb.y, hb.z, hb.w};
    #pragma unroll
    for (int kk = 0; kk < 4; ++kk) {
      float4 w = *reinterpret_cast<const float4*>(&W[(size_t)(k4 + kk) * DDIM + col]);
      acc[0][0] = fmaf(hav[kk], w.x, acc[0][0]);
      acc[0][1] = fmaf(hav[kk], w.y, acc[0][1]);
      acc[0][2] = fmaf(hav[kk], w.z, acc[0][2]);
      acc[0][3] = fmaf(hav[kk], w.w, acc[0][3]);
      acc[1][0] = fmaf(hbv[kk], w.x, acc[1][0]);
      acc[1][1] = fmaf(hbv[kk], w.y, acc[1][1]);
      acc[1][2] = fmaf(hbv[kk], w.z, acc[1][2]);
      acc[1][3] = fmaf(hbv[kk], w.w, acc[1][3]);
    }
  }

  if (mat == 1) {
    #pragma unroll
    for (int rr = 0; rr < 2; ++rr) {
      const int r = ra + rr;
      #pragma unroll
      for (int c = 0; c < 4; ++c) {
        float z = acc[rr][c] + bsg[col + c];
        float s = (z > 0.f ? z + 1.0f : __expf(z)) + 1e-14f;
        sig[r][col + c] = s;
      }
    }
  }
  __syncthreads();

  float qp[2] = {0.f, 0.f};
  if (mat == 0) {
    #pragma unroll
    for (int rr = 0; rr < 2; ++rr) {
      const int r = ra + rr;
      const int row = r0 + r;
      float4 sv = *reinterpret_cast<const float4*>(&sig[r][col]);
      const float svv[4] = {sv.x, sv.y, sv.z, sv.w};
      float f1[4], f2[4], f3[4], f4[4];
      #pragma unroll
      for (int c = 0; c < 4; ++c) {
        float mu  = acc[rr][c] + bmu[col + c];
        float s   = svv[c];
        float inv = 1.0f / s;
        f1[c] = inv;
        f2[c] = s + mu * mu;
        f3[c] = -2.0f * mu * inv;
        f4[c] = mu;
        qp[rr] += mu * mu * inv;
      }
      *reinterpret_cast<float4*>(&Mu[(size_t)row * DDIM + col]) =
          make_float4(f4[0], f4[1], f4[2], f4[3]);
      const float* blocks[4] = {f1, f2, f3, f4};
      #pragma unroll
      for (int b = 0; b < 4; ++b) {
        const float* v = blocks[b];
        unsigned short h[4], l[4];
        #pragma unroll
        for (int c = 0; c < 4; ++c) {
          h[c] = bfhi(v[c]);
          l[c] = bfhi(v[c] - bf2f(h[c]));
        }
        size_t off = (size_t)row * FEAT + b * 128 + col;
        *reinterpret_cast<ushort4*>(&Fhi[off]) = make_ushort4(h[0], h[1], h[2], h[3]);
        *reinterpret_cast<ushort4*>(&Flo[off]) = make_ushort4(l[0], l[1], l[2], l[3]);
      }
    }
  }
  #pragma unroll
  for (int o = 16; o; o >>= 1) {
    qp[0] += __shfl_xor(qp[0], o, 32);
    qp[1] += __shfl_xor(qp[1], o, 32);
  }
  if (cg == 0) {
    qout[r0 + ra] = qp[0];
    qout[r0 + rb] = qp[1];
  }
}

// ---------------------------------------------------------------------------
// k_hash2: per-dimension duplicate detection in an LDS hash.
// One block per dim d (128 blocks). 2048 inserts into 4096 slots (load 0.5).
// ---------------------------------------------------------------------------
__global__ __launch_bounds__(256) void k_hash2(const float* __restrict__ Mu,
                                               int* __restrict__ rowflag,
                                               int* __restrict__ dupcnt,
                                               int2* __restrict__ duplist) {
  __shared__ unsigned long long tabL[4096];   // 32 KB
  const int d = blockIdx.x;
  const int t = threadIdx.x;
  #pragma unroll
  for (int k = 0; k < 16; ++k) tabL[t + 256 * k] = 0ULL;
  __syncthreads();
  #pragma unroll
  for (int k = 0; k < 8; ++k) {
    const int r = t + 256 * k;
    unsigned int bits = __float_as_uint(Mu[(size_t)r * DDIM + d]);
    if (bits == 0x80000000u) bits = 0u;       // -0.0 == +0.0
    unsigned int h = bits * 2654435761u; h ^= h >> 16; h &= 4095u;
    const unsigned long long me =
        ((unsigned long long)bits << 32) | (unsigned int)(r + 1);
    for (;;) {
      unsigned long long old = atomicCAS(&tabL[h], 0ULL, me);
      if (old == 0ULL) break;
      if ((unsigned int)(old >> 32) == bits) {
        int r2 = (int)(old & 0xffffffffu) - 1;
        rowflag[r] = 1; rowflag[r2] = 1;
        int e = atomicAdd(dupcnt, 1);
        if (e < DCAP) duplist[e] = make_int2(min(r, r2), max(r, r2));
      }
      h = (h + 1u) & 4095u;
    }
  }
}

// ---------------------------------------------------------------------------
// K2: split-bf16 MFMA all-pairs (virtual K=1536) + NT-Xent epilogue.
// Tile 128x64, grid 16x32 = 512 blocks (2/CU). 4 waves (2x2), wave 64x32.
// Per K-block: stage Ahi|Alo|Bhi|Blo (48 KB) ONCE via global_load_lds with
// pre-swizzled global source (linear LDS dest), then 3 terms x 16 MFMA x 2kc.
// ---------------------------------------------------------------------------
__global__ __launch_bounds__(256) void k2_mfma(
    const unsigned short* __restrict__ Fhi, const unsigned short* __restrict__ Flo,
    const float* __restrict__ qv, const int* __restrict__ labels,
    const int* __restrict__ msk, const int* __restrict__ rowflag,
    const int* __restrict__ dupcnt, const int2* __restrict__ duplist,
    float4* __restrict__ partials)
{
  // ushort offsets: Ahi 0, Alo 8192, Bhi 16384, Blo 20480  (48 KB total)
  __shared__ unsigned short lds[24576];
  __shared__ float qiL[128], qjL[64];
  __shared__ int livL[128], ljvL[64], fliL[128], fljL[64];

  const int t = threadIdx.x;
  const int bi = blockIdx.x, bj = blockIdx.y;
  const int i0 = bi * 128, j0 = bj * 64;

  if (t < 128) {
    int i = i0 + t;
    qiL[t] = qv[i];
    livL[t] = (msk[i] == 1 && labels[i] >= 0) ? labels[i] : -1;
    fliL[t] = rowflag[i];
  } else if (t < 192) {
    int j = j0 + (t - 128);
    qjL[t - 128] = qv[j];
    ljvL[t - 128] = (msk[j] == 1 && labels[j] >= 0) ? labels[j] : -1;
    fljL[t - 128] = rowflag[j];
  }

  // staging setup: 3072 16B-slots, 12 reps of 256 threads.
  // slots [0,1024): Ahi  [1024,2048): Alo  [2048,2560): Bhi  [2560,3072): Blo
  const unsigned short* gsrc[12];
  unsigned short* lp[12];
  #pragma unroll
  for (int rr = 0; rr < 12; ++rr) {
    const int s = rr * 256 + t;
    lp[rr] = &lds[(size_t)(rr * 256 + (t & 192)) << 3];   // wave-uniform base
    if (rr < 8) {
      const int si = s & 1023;
      const int row = si >> 3, c8 = si & 7;
      const unsigned short* F = (rr < 4) ? Fhi : Flo;
      gsrc[rr] = F + (size_t)(i0 + row) * FEAT + ((c8 ^ (row & 7)) << 3);
    } else {
      const int si = (s - 2048) & 511;
      const int row = si >> 3, c8 = si & 7;
      const unsigned short* F = (rr < 10) ? Fhi : Flo;
      gsrc[rr] = F + (size_t)(j0 + row) * FEAT + ((c8 ^ (row & 7)) << 3);
    }
  }

  f32x4 acc[4][2];
  #pragma unroll
  for (int a = 0; a < 4; ++a)
    #pragma unroll
    for (int b = 0; b < 2; ++b) {
      acc[a][b][0] = 0.f; acc[a][b][1] = 0.f; acc[a][b][2] = 0.f; acc[a][b][3] = 0.f;
    }

  const int wid = t >> 6, lane = t & 63;
  const int wr = wid >> 1, wc = wid & 1;
  const int gq = lane >> 4, c0 = lane & 15;

  for (int kblk = 0; kblk < 8; ++kblk) {
    const int kbA = kblk * 64;
    const int kbB = kbA ^ 128;          // feature-block swap on B side
    __syncthreads();                    // prev tile fully consumed
    #pragma unroll
    for (int rr = 0; rr < 12; ++rr)
      gload16(gsrc[rr] + (rr < 8 ? kbA : kbB), lp[rr]);
    __syncthreads();                    // drains vmcnt -> LDS ready
    #pragma unroll
    for (int kc = 0; kc < 2; ++kc) {
      const int cb = kc * 4 + gq;
      bf16x8 ahi[4], alo[4], bhi[2], blo[2];
      #pragma unroll
      for (int fa = 0; fa < 4; ++fa) {
        const int row = wr * 64 + fa * 16 + c0;
        const int idx = row * 64 + ((cb ^ (row & 7)) << 3);
        ahi[fa] = *reinterpret_cast<const bf16x8*>(&lds[idx]);
        alo[fa] = *reinterpret_cast<const bf16x8*>(&lds[8192 + idx]);
      }
      #pragma unroll
      for (int fb = 0; fb < 2; ++fb) {
        const int row = wc * 32 + fb * 16 + c0;
        const int idx = row * 64 + ((cb ^ (row & 7)) << 3);
        bhi[fb] = *reinterpret_cast<const bf16x8*>(&lds[16384 + idx]);
        blo[fb] = *reinterpret_cast<const bf16x8*>(&lds[20480 + idx]);
      }
      #pragma unroll
      for (int fa = 0; fa < 4; ++fa)
        #pragma unroll
        for (int fb = 0; fb < 2; ++fb) {
          acc[fa][fb] = __builtin_amdgcn_mfma_f32_16x16x32_bf16(ahi[fa], bhi[fb], acc[fa][fb], 0, 0, 0);
          acc[fa][fb] = __builtin_amdgcn_mfma_f32_16x16x32_bf16(ahi[fa], blo[fb], acc[fa][fb], 0, 0, 0);
          acc[fa][fb] = __builtin_amdgcn_mfma_f32_16x16x32_bf16(alo[fa], bhi[fb], acc[fa][fb], 0, 0, 0);
        }
    }
  }

  // ---- epilogue: NT-Xent online merge per output row ----
  const int ndup = min(*dupcnt, DCAP);
  #pragma unroll
  for (int fa = 0; fa < 4; ++fa) {
    #pragma unroll
    for (int r = 0; r < 4; ++r) {
      const int iloc = wr * 64 + fa * 16 + gq * 4 + r;   // D row (m89 mapping)
      const int gi = i0 + iloc;
      const int li = livL[iloc];
      const float qi = qiL[iloc];
      const int fi = fliL[iloc];
      float m = -INFINITY, n = 0.f, d = 0.f, c = 0.f;
      if (li >= 0) {
        #pragma unroll
        for (int fb = 0; fb < 2; ++fb) {
          const int jloc = wc * 32 + fb * 16 + c0;       // D col
          const int gj = j0 + jloc;
          const int lj = ljvL[jloc];
          bool inc = (lj >= 0) && (gi != gj);
          if (inc && fi && fljL[jloc]) {
            int plo = min(gi, gj), phi = max(gi, gj);
            for (int e = 0; e < ndup; ++e) {
              int2 p = duplist[e];
              if (p.x == plo && p.y == phi) { inc = false; break; }
            }
          }
          if (inc) {
            float S = acc[fa][fb][r];
            float l = 64.0f - 0.25f * (qi + qjL[jloc] + S);
            float w = (li == lj) ? 1.0f : 0.0f;
            mergeState(m, n, d, l, w, 1.0f);
            c += w;
          }
        }
      }
      #pragma unroll
      for (int o = 1; o < 16; o <<= 1) {
        float m2 = __shfl_xor(m, o);
        float n2 = __shfl_xor(n, o);
        float d2 = __shfl_xor(d, o);
        float c2 = __shfl_xor(c, o);
        mergeState(m, n, d, m2, n2, d2);
        c += c2;
      }
      if (c0 == 0)
        partials[(size_t)(bj * 2 + wc) * NROWS + gi] = make_float4(m, n, d, c);
    }
  }
}

// ---------------------------------------------------------------------------
// K3a: merge 64 j-slices per row, per-block partial sums (no atomics).
// ---------------------------------------------------------------------------
__global__ __launch_bounds__(256) void k3a(const float4* __restrict__ partials,
                                           float2* __restrict__ bsums)
{
  const int r = blockIdx.x * 256 + threadIdx.x;
  float m = -INFINITY, n = 0.f, d = 0.f, c = 0.f;
  #pragma unroll 8
  for (int js = 0; js < 64; ++js) {
    float4 p = partials[(size_t)js * NROWS + r];
    mergeState(m, n, d, p.x, p.y, p.z);
    c += p.w;
  }
  float lf = 0.f, ns = 0.f;
  if (c > 0.f) {
    lf = log2f(d) - log2f(n) + log2f(c);
    ns = 1.f;
  }
  #pragma unroll
  for (int o = 32; o; o >>= 1) {
    lf += __shfl_down(lf, o);
    ns += __shfl_down(ns, o);
  }
  __shared__ float sl[4], sn[4];
  const int wid = threadIdx.x >> 6;
  if ((threadIdx.x & 63) == 0) { sl[wid] = lf; sn[wid] = ns; }
  __syncthreads();
  if (threadIdx.x == 0)
    bsums[blockIdx.x] = make_float2(sl[0] + sl[1] + sl[2] + sl[3],
                                    sn[0] + sn[1] + sn[2] + sn[3]);
}

__global__ __launch_bounds__(64) void k3b(const float2* __restrict__ bsums,
                                          float* __restrict__ out)
{
  if (threadIdx.x == 0) {
    float L = 0.f, C = 0.f;
    for (int b = 0; b < 8; ++b) { L += bsums[b].x; C += bsums[b].y; }
    out[0] = L / fmaxf(C, 1.0f);
  }
}

// ---------------------------------------------------------------------------
extern "C" void kernel_launch(void* const* d_in, const int* in_sizes, int n_in,
                              void* d_out, int out_size, void* d_ws, size_t ws_size,
                              hipStream_t stream) {
  const float* E   = (const float*)d_in[0];
  const int*   tid = (const int*)d_in[1];
  const int*   msk = (const int*)d_in[2];
  const float* Wmu = (const float*)d_in[3];
  const float* bmu = (const float*)d_in[4];
  const float* Wsg = (const float*)d_in[5];
  const float* bsg = (const float*)d_in[6];

  unsigned char* w = (unsigned char*)d_ws;
  unsigned short* Fhi = (unsigned short*)w;   w += (size_t)NROWS * FEAT * 2;   // 2 MB
  unsigned short* Flo = (unsigned short*)w;   w += (size_t)NROWS * FEAT * 2;   // 2 MB
  float* Mu           = (float*)w;            w += (size_t)NROWS * DDIM * 4;   // 1 MB
  float* qv           = (float*)w;            w += (size_t)NROWS * 4;
  int* rowflag        = (int*)w;              w += (size_t)NROWS * 4;
  int* dupcnt         = (int*)w;              w += 256;
  float2* bsums       = (float2*)w;           w += 256;
  int2* duplist       = (int2*)w;             w += (size_t)DCAP * 8;
  float4* partials    = (float4*)w;           w += (size_t)64 * NROWS * 16;    // 2 MB

  k1_project<<<NROWS / 8, 256, 0, stream>>>(E, Wmu, bmu, Wsg, bsg, Mu, Fhi, Flo,
                                            qv, rowflag, dupcnt);
  k_hash2<<<DDIM, 256, 0, stream>>>(Mu, rowflag, dupcnt, duplist);
  k2_mfma<<<dim3(16, 32), 256, 0, stream>>>(Fhi, Flo, qv, tid, msk, rowflag,
                                            dupcnt, duplist, partials);
  k3a<<<8, 256, 0, stream>>>(partials, bsums);
  k3b<<<1, 64, 0, stream>>>(bsums, (float*)d_out);
}

// Round 4
// 65.885 us; speedup vs baseline: 2.6914x; 1.3278x over previous
//
#include <hip/hip_runtime.h>
#include <math.h>

#define NROWS 2048
#define HDIM 768
#define DDIM 128
#define FEAT 512
#define DCAP 2048
#define TSLOTS 8192

typedef __attribute__((ext_vector_type(8))) short bf16x8;
typedef __attribute__((ext_vector_type(4))) float f32x4;

// Online logsumexp-style merge: state (m, n, d) <- merge with (m2, n2, d2).
__device__ __forceinline__ void mergeState(float& m, float& n, float& d,
                                           float m2, float n2, float d2) {
  float M = fmaxf(m, m2);
  float s1 = (m >= M) ? 1.0f : __expf(m - M);
  float s2 = (m2 >= M) ? 1.0f : __expf(m2 - M);
  n = n * s1 + n2 * s2;
  d = d * s1 + d2 * s2;
  m = M;
}

__device__ __forceinline__ unsigned short bfhi(float x) {
  unsigned int u = __float_as_uint(x);
  return (unsigned short)((u + 0x7fffu + ((u >> 16) & 1u)) >> 16);
}
__device__ __forceinline__ float bf2f(unsigned short h) {
  return __uint_as_float(((unsigned int)h) << 16);
}

__device__ __forceinline__ void gload16(const void* g, void* l) {
  __builtin_amdgcn_global_load_lds(
      (const __attribute__((address_space(1))) void*)g,
      (__attribute__((address_space(3))) void*)l, 16, 0, 0);
}

// ---------------------------------------------------------------------------
// k0_prep: (a) Ehi/Elo = bf16-split of relu(E); (b) Wthi/Wtlo = bf16-split of
// [Wmu|Wsg] transposed to [256 cols][768 k]; (c) clear hash table/flags.
// ---------------------------------------------------------------------------
__global__ __launch_bounds__(256) void k0_prep(
    const float* __restrict__ E, const float* __restrict__ Wmu,
    const float* __restrict__ Wsg,
    unsigned short* __restrict__ Ehi, unsigned short* __restrict__ Elo,
    unsigned short* __restrict__ Wthi, unsigned short* __restrict__ Wtlo,
    unsigned long long* __restrict__ tab, int* __restrict__ rowflag,
    int* __restrict__ dupcnt)
{
  const int bid = blockIdx.x, t = threadIdx.x;
  if (bid < 768) {
    const int base = bid * 2048 + t * 8;
    float4 v0 = *reinterpret_cast<const float4*>(E + base);
    float4 v1 = *reinterpret_cast<const float4*>(E + base + 4);
    const float v[8] = {v0.x, v0.y, v0.z, v0.w, v1.x, v1.y, v1.z, v1.w};
    unsigned short h[8], l[8];
    #pragma unroll
    for (int i = 0; i < 8; ++i) {
      float f = fmaxf(v[i], 0.f);
      h[i] = bfhi(f);
      l[i] = bfhi(f - bf2f(h[i]));
    }
    *reinterpret_cast<ushort4*>(Ehi + base)     = make_ushort4(h[0], h[1], h[2], h[3]);
    *reinterpret_cast<ushort4*>(Ehi + base + 4) = make_ushort4(h[4], h[5], h[6], h[7]);
    *reinterpret_cast<ushort4*>(Elo + base)     = make_ushort4(l[0], l[1], l[2], l[3]);
    *reinterpret_cast<ushort4*>(Elo + base + 4) = make_ushort4(l[4], l[5], l[6], l[7]);
  } else if (bid < 864) {
    const int tid = (bid - 768) * 256 + t;          // 0..24575
    const int c = tid / 96, kc = (tid % 96) * 8;
    unsigned short h[8], l[8];
    #pragma unroll
    for (int j = 0; j < 8; ++j) {
      float w = (c < 128) ? Wmu[(size_t)(kc + j) * DDIM + c]
                          : Wsg[(size_t)(kc + j) * DDIM + (c - 128)];
      h[j] = bfhi(w);
      l[j] = bfhi(w - bf2f(h[j]));
    }
    const size_t o = (size_t)c * HDIM + kc;
    *reinterpret_cast<ushort4*>(Wthi + o)     = make_ushort4(h[0], h[1], h[2], h[3]);
    *reinterpret_cast<ushort4*>(Wthi + o + 4) = make_ushort4(h[4], h[5], h[6], h[7]);
    *reinterpret_cast<ushort4*>(Wtlo + o)     = make_ushort4(l[0], l[1], l[2], l[3]);
    *reinterpret_cast<ushort4*>(Wtlo + o + 4) = make_ushort4(l[4], l[5], l[6], l[7]);
  } else if (bid < 872) {
    const int i4 = (bid - 864) * 1024 + t * 4;
    #pragma unroll
    for (int k = 0; k < 4; ++k) tab[i4 + k] = 0ULL;
    rowflag[(bid - 864) * 256 + t] = 0;
  } else {
    if (t == 0) dupcnt[0] = 0;
  }
}

// ---------------------------------------------------------------------------
// k1m: split-K MFMA projection GEMM. C[2048][256] partials over 4 K-splits.
// Block: M-tile 64, N-tile 128, K-split 192. 256 threads (2x2 waves).
// dbuf LDS (2 x 24 KB), pipelined with counted vmcnt(6).
// ---------------------------------------------------------------------------
__global__ __launch_bounds__(256) void k1m(
    const unsigned short* __restrict__ Ehi, const unsigned short* __restrict__ Elo,
    const unsigned short* __restrict__ Wthi, const unsigned short* __restrict__ Wtlo,
    float* __restrict__ Cpart)
{
  __shared__ unsigned short lds[24576];   // 48 KB = 2 buf x 12288
  const int t = threadIdx.x;
  const int bid = blockIdx.x;
  const int mt = bid & 31, nt = (bid >> 5) & 1, ks = bid >> 6;
  const int i0 = mt * 64, n0 = nt * 128, kbase = ks * 192;

  // staging: rr 0..5. regions (ushort base): Ahi 0, Alo 2048, Bhi 4096, Blo 8192
  const unsigned short* gF[6];
  size_t goff[6];
  int lpb[6];
  #pragma unroll
  for (int rr = 0; rr < 6; ++rr) {
    if (rr < 2) {
      const int s = t, gq = s >> 6, row = s & 63;
      gF[rr] = rr ? Elo : Ehi;
      goff[rr] = (size_t)(i0 + row) * HDIM + kbase + gq * 8;
      lpb[rr] = rr * 2048 + (s & ~63) * 8;
    } else {
      const int s = (rr & 1) * 256 + t, gq = s >> 7, row = s & 127;
      gF[rr] = (rr >= 4) ? Wtlo : Wthi;
      goff[rr] = (size_t)(n0 + row) * HDIM + kbase + gq * 8;
      lpb[rr] = (rr >= 4 ? 8192 : 4096) + (s & ~63) * 8;
    }
  }

  f32x4 acc[2][4];
  #pragma unroll
  for (int a = 0; a < 2; ++a)
    #pragma unroll
    for (int b = 0; b < 4; ++b) {
      acc[a][b][0] = 0.f; acc[a][b][1] = 0.f; acc[a][b][2] = 0.f; acc[a][b][3] = 0.f;
    }

  const int wid = t >> 6, lane = t & 63;
  const int wr = wid >> 1, wc = wid & 1;
  const int gq = lane >> 4, c0 = lane & 15;

  auto stage = [&](int it, int buf) {
    unsigned short* lb = lds + buf * 12288;
    #pragma unroll
    for (int rr = 0; rr < 6; ++rr)
      gload16(gF[rr] + goff[rr] + it * 32, lb + lpb[rr]);
  };

  stage(0, 0);
  __syncthreads();

  for (int it = 0; it < 6; ++it) {
    if (it < 5) {
      stage(it + 1, (it + 1) & 1);
      asm volatile("s_waitcnt vmcnt(6)" ::: "memory");
    } else {
      asm volatile("s_waitcnt vmcnt(0)" ::: "memory");
    }
    __builtin_amdgcn_s_barrier();
    {
      const unsigned short* lb = lds + (it & 1) * 12288;
      bf16x8 ah[2], al[2], bh[4], bl[4];
      #pragma unroll
      for (int fa = 0; fa < 2; ++fa) {
        const int ia = gq * 512 + (wr * 32 + fa * 16 + c0) * 8;
        ah[fa] = *reinterpret_cast<const bf16x8*>(lb + ia);
        al[fa] = *reinterpret_cast<const bf16x8*>(lb + 2048 + ia);
      }
      #pragma unroll
      for (int fb = 0; fb < 4; ++fb) {
        const int ib = gq * 1024 + (wc * 64 + fb * 16 + c0) * 8;
        bh[fb] = *reinterpret_cast<const bf16x8*>(lb + 4096 + ib);
        bl[fb] = *reinterpret_cast<const bf16x8*>(lb + 8192 + ib);
      }
      #pragma unroll
      for (int fa = 0; fa < 2; ++fa)
        #pragma unroll
        for (int fb = 0; fb < 4; ++fb) {
          acc[fa][fb] = __builtin_amdgcn_mfma_f32_16x16x32_bf16(ah[fa], bh[fb], acc[fa][fb], 0, 0, 0);
          acc[fa][fb] = __builtin_amdgcn_mfma_f32_16x16x32_bf16(ah[fa], bl[fb], acc[fa][fb], 0, 0, 0);
          acc[fa][fb] = __builtin_amdgcn_mfma_f32_16x16x32_bf16(al[fa], bh[fb], acc[fa][fb], 0, 0, 0);
        }
    }
    __builtin_amdgcn_s_barrier();
  }

  #pragma unroll
  for (int fa = 0; fa < 2; ++fa)
    #pragma unroll
    for (int fb = 0; fb < 4; ++fb)
      #pragma unroll
      for (int r = 0; r < 4; ++r) {
        const int row = i0 + wr * 32 + fa * 16 + gq * 4 + r;
        const int col = n0 + wc * 64 + fb * 16 + c0;
        Cpart[((size_t)ks * NROWS + row) * 256 + col] = acc[fa][fb][r];
      }
}

// ---------------------------------------------------------------------------
// k1e: reduce 4 K-split partials -> mu/sigma -> features Fhi/Flo, q, and
// full-mu-vector duplicate hash (rowflag/duplist). Block = 4 rows.
// ---------------------------------------------------------------------------
__global__ __launch_bounds__(256) void k1e(
    const float* __restrict__ Cpart, const float* __restrict__ bmu,
    const float* __restrict__ bsg,
    unsigned short* __restrict__ Fhi, unsigned short* __restrict__ Flo,
    float* __restrict__ qout, unsigned long long* __restrict__ tab,
    int* __restrict__ rowflag, int* __restrict__ dupcnt,
    int2* __restrict__ duplist)
{
  __shared__ float sigL[4][DDIM];
  const int t = threadIdx.x;
  const int row = t >> 6, cg = t & 63, c4 = cg * 4;
  const int mat = c4 >> 7, colm = c4 & 127;
  const int rg = blockIdx.x * 4 + row;

  float v[4];
  {
    float4 s0 = *reinterpret_cast<const float4*>(&Cpart[((size_t)0 * NROWS + rg) * 256 + c4]);
    float4 s1 = *reinterpret_cast<const float4*>(&Cpart[((size_t)1 * NROWS + rg) * 256 + c4]);
    float4 s2 = *reinterpret_cast<const float4*>(&Cpart[((size_t)2 * NROWS + rg) * 256 + c4]);
    float4 s3 = *reinterpret_cast<const float4*>(&Cpart[((size_t)3 * NROWS + rg) * 256 + c4]);
    v[0] = ((s0.x + s1.x) + s2.x) + s3.x;
    v[1] = ((s0.y + s1.y) + s2.y) + s3.y;
    v[2] = ((s0.z + s1.z) + s2.z) + s3.z;
    v[3] = ((s0.w + s1.w) + s2.w) + s3.w;
  }

  if (mat == 1) {
    #pragma unroll
    for (int c = 0; c < 4; ++c) {
      float z = v[c] + bsg[colm + c];
      float s = (z > 0.f ? z + 1.0f : __expf(z)) + 1e-14f;
      sigL[row][colm + c] = s;
    }
  }
  __syncthreads();

  float q = 0.f;
  unsigned int hx = 0u, hs = 0u;
  if (mat == 0) {
    float f1[4], f2[4], f3[4], f4[4];
    #pragma unroll
    for (int c = 0; c < 4; ++c) {
      float mu = v[c] + bmu[colm + c];
      float s  = sigL[row][colm + c];
      float inv = 1.0f / s;
      f1[c] = inv;
      f2[c] = s + mu * mu;
      f3[c] = -2.0f * mu * inv;
      f4[c] = mu;
      q += mu * mu * inv;
      unsigned int b = __float_as_uint(mu);
      if (b == 0x80000000u) b = 0u;
      unsigned int hm = (b ^ ((unsigned int)(colm + c) * 0x9E3779B9u)) * 0x85EBCA6Bu;
      hm ^= hm >> 13;
      hx ^= hm;
      hs += hm * 0xC2B2AE35u;
    }
    const float* blocks[4] = {f1, f2, f3, f4};
    #pragma unroll
    for (int b = 0; b < 4; ++b) {
      const float* vv = blocks[b];
      unsigned short h[4], l[4];
      #pragma unroll
      for (int c = 0; c < 4; ++c) {
        h[c] = bfhi(vv[c]);
        l[c] = bfhi(vv[c] - bf2f(h[c]));
      }
      size_t off = (size_t)rg * FEAT + b * 128 + colm;
      *reinterpret_cast<ushort4*>(&Fhi[off]) = make_ushort4(h[0], h[1], h[2], h[3]);
      *reinterpret_cast<ushort4*>(&Flo[off]) = make_ushort4(l[0], l[1], l[2], l[3]);
    }
  }
  #pragma unroll
  for (int o = 16; o; o >>= 1) q += __shfl_xor(q, o, 32);
  #pragma unroll
  for (int o = 1; o < 32; o <<= 1) {
    hx ^= (unsigned int)__shfl_xor((int)hx, o, 32);
    hs += (unsigned int)__shfl_xor((int)hs, o, 32);
  }
  if (cg == 0) {
    qout[rg] = q;
    unsigned long long key = (((unsigned long long)hx << 32) | hs) & ~0xFFFULL;
    if (key == 0ULL) key = 0x123456789000ULL;
    const unsigned long long me = key | (unsigned long long)(rg + 1);
    unsigned int h = (hx ^ (hs * 0x9E3779B9u)) & (TSLOTS - 1);
    for (;;) {
      unsigned long long old = atomicCAS(&tab[h], 0ULL, me);
      if (old == 0ULL) break;
      if ((old & ~0xFFFULL) == key) {
        int r2 = (int)(old & 0xFFFULL) - 1;
        rowflag[rg] = 1; rowflag[r2] = 1;
        int e = atomicAdd(dupcnt, 1);
        if (e < DCAP) duplist[e] = make_int2(min(rg, r2), max(rg, r2));
      }
      h = (h + 1u) & (TSLOTS - 1);
    }
  }
}

// ---------------------------------------------------------------------------
// K2: split-bf16 MFMA all-pairs (virtual K=1536) + NT-Xent epilogue.
// Tile 128x128, grid 16x16, 512 threads (2x4 waves, wave 64x32).
// dbuf LDS 2x32KB at 32-K granularity; counted vmcnt(4), raw barriers.
// K-major LDS layout [gq][row] -> conflict-free, no swizzle.
// ---------------------------------------------------------------------------
__global__ __launch_bounds__(512) void k2_mfma(
    const unsigned short* __restrict__ Fhi, const unsigned short* __restrict__ Flo,
    const float* __restrict__ qv, const int* __restrict__ labels,
    const int* __restrict__ msk, const int* __restrict__ rowflag,
    const int* __restrict__ dupcnt, const int2* __restrict__ duplist,
    float4* __restrict__ partials)
{
  __shared__ unsigned short lds[32768];   // 64 KB = 2 buf x 16384
  const int t = threadIdx.x;
  const int bi = blockIdx.x, bj = blockIdx.y;
  const int i0 = bi * 128, j0 = bj * 128;
  const int wid = t >> 6, lane = t & 63;
  const int wr = wid >> 2, wc = wid & 3;      // 2 x 4 waves, wave tile 64x32
  const int gq = lane >> 4, c0 = lane & 15;

  // staging: slot = t (512 slots/region): gq = t>>7, row = t&127
  const int srow = t & 127, sgq = t >> 7;
  const size_t offA = (size_t)(i0 + srow) * FEAT + sgq * 8;
  const size_t offB = (size_t)(j0 + srow) * FEAT + sgq * 8;
  const int lpb = (t & 448) * 8;              // wave-uniform within-region base

  auto stage = [&](int hb, int buf) {
    const int kA = hb * 32;
    const int kB = kA ^ 128;                  // feature-block swap on B side
    unsigned short* lb = lds + buf * 16384;
    gload16(Fhi + offA + kA, lb + lpb);           // Ahi
    gload16(Flo + offA + kA, lb + 4096 + lpb);    // Alo
    gload16(Fhi + offB + kB, lb + 8192 + lpb);    // Bhi
    gload16(Flo + offB + kB, lb + 12288 + lpb);   // Blo
  };

  f32x4 acc[4][2];
  #pragma unroll
  for (int a = 0; a < 4; ++a)
    #pragma unroll
    for (int b = 0; b < 2; ++b) {
      acc[a][b][0] = 0.f; acc[a][b][1] = 0.f; acc[a][b][2] = 0.f; acc[a][b][3] = 0.f;
    }

  stage(0, 0);
  __syncthreads();

  for (int hb = 0; hb < 16; ++hb) {
    if (hb < 15) {
      stage(hb + 1, (hb + 1) & 1);
      asm volatile("s_waitcnt vmcnt(4)" ::: "memory");
    } else {
      asm volatile("s_waitcnt vmcnt(0)" ::: "memory");
    }
    __builtin_amdgcn_s_barrier();
    {
      const unsigned short* lb = lds + (hb & 1) * 16384;
      bf16x8 ah[4], al[4], bh[2], bl[2];
      #pragma unroll
      for (int fa = 0; fa < 4; ++fa) {
        const int ia = gq * 1024 + (wr * 64 + fa * 16 + c0) * 8;
        ah[fa] = *reinterpret_cast<const bf16x8*>(lb + ia);
        al[fa] = *reinterpret_cast<const bf16x8*>(lb + 4096 + ia);
      }
      #pragma unroll
      for (int fb = 0; fb < 2; ++fb) {
        const int ib = gq * 1024 + (wc * 32 + fb * 16 + c0) * 8;
        bh[fb] = *reinterpret_cast<const bf16x8*>(lb + 8192 + ib);
        bl[fb] = *reinterpret_cast<const bf16x8*>(lb + 12288 + ib);
      }
      #pragma unroll
      for (int fa = 0; fa < 4; ++fa)
        #pragma unroll
        for (int fb = 0; fb < 2; ++fb) {
          acc[fa][fb] = __builtin_amdgcn_mfma_f32_16x16x32_bf16(ah[fa], bh[fb], acc[fa][fb], 0, 0, 0);
          acc[fa][fb] = __builtin_amdgcn_mfma_f32_16x16x32_bf16(ah[fa], bl[fb], acc[fa][fb], 0, 0, 0);
          acc[fa][fb] = __builtin_amdgcn_mfma_f32_16x16x32_bf16(al[fa], bh[fb], acc[fa][fb], 0, 0, 0);
        }
    }
    __builtin_amdgcn_s_barrier();
  }

  // ---- epilogue: NT-Xent online merge per output row (aux read from global) --
  const int ndup = min(dupcnt[0], DCAP);
  int ljv[2]; float qjv[2]; int fjv[2]; int gjv[2];
  #pragma unroll
  for (int fb = 0; fb < 2; ++fb) {
    const int gj = j0 + wc * 32 + fb * 16 + c0;
    const int lab = labels[gj];
    ljv[fb] = (msk[gj] == 1 && lab >= 0) ? lab : -1;
    qjv[fb] = qv[gj];
    fjv[fb] = rowflag[gj];
    gjv[fb] = gj;
  }
  #pragma unroll
  for (int fa = 0; fa < 4; ++fa) {
    const int ibase = i0 + wr * 64 + fa * 16 + gq * 4;
    int li4[4], mi4[4], fi4[4]; float qi4[4];
    *reinterpret_cast<int4*>(li4)   = *reinterpret_cast<const int4*>(labels + ibase);
    *reinterpret_cast<int4*>(mi4)   = *reinterpret_cast<const int4*>(msk + ibase);
    *reinterpret_cast<int4*>(fi4)   = *reinterpret_cast<const int4*>(rowflag + ibase);
    *reinterpret_cast<float4*>(qi4) = *reinterpret_cast<const float4*>(qv + ibase);
    #pragma unroll
    for (int r = 0; r < 4; ++r) {
      const int gi = ibase + r;
      const int li = (mi4[r] == 1 && li4[r] >= 0) ? li4[r] : -1;
      float m = -INFINITY, n = 0.f, d = 0.f, c = 0.f;
      if (li >= 0) {
        #pragma unroll
        for (int fb = 0; fb < 2; ++fb) {
          const int lj = ljv[fb];
          bool inc = (lj >= 0) && (gi != gjv[fb]);
          if (inc && fi4[r] && fjv[fb]) {
            int plo = min(gi, gjv[fb]), phi = max(gi, gjv[fb]);
            for (int e = 0; e < ndup; ++e) {
              int2 p = duplist[e];
              if (p.x == plo && p.y == phi) { inc = false; break; }
            }
          }
          if (inc) {
            float S = acc[fa][fb][r];
            float l = 64.0f - 0.25f * (qi4[r] + qjv[fb] + S);
            float w = (li == lj) ? 1.0f : 0.0f;
            mergeState(m, n, d, l, w, 1.0f);
            c += w;
          }
        }
      }
      #pragma unroll
      for (int o = 1; o < 16; o <<= 1) {
        float m2 = __shfl_xor(m, o);
        float n2 = __shfl_xor(n, o);
        float d2 = __shfl_xor(d, o);
        float c2 = __shfl_xor(c, o);
        mergeState(m, n, d, m2, n2, d2);
        c += c2;
      }
      if (c0 == 0)
        partials[(size_t)(bj * 4 + wc) * NROWS + gi] = make_float4(m, n, d, c);
    }
  }
}

// ---------------------------------------------------------------------------
// K3a: merge 64 j-slices per row, per-block partial sums (no atomics).
// ---------------------------------------------------------------------------
__global__ __launch_bounds__(256) void k3a(const float4* __restrict__ partials,
                                           float2* __restrict__ bsums)
{
  const int r = blockIdx.x * 256 + threadIdx.x;
  float m = -INFINITY, n = 0.f, d = 0.f, c = 0.f;
  #pragma unroll 8
  for (int js = 0; js < 64; ++js) {
    float4 p = partials[(size_t)js * NROWS + r];
    mergeState(m, n, d, p.x, p.y, p.z);
    c += p.w;
  }
  float lf = 0.f, ns = 0.f;
  if (c > 0.f) {
    lf = log2f(d) - log2f(n) + log2f(c);
    ns = 1.f;
  }
  #pragma unroll
  for (int o = 32; o; o >>= 1) {
    lf += __shfl_down(lf, o);
    ns += __shfl_down(ns, o);
  }
  __shared__ float sl[4], sn[4];
  const int wid = threadIdx.x >> 6;
  if ((threadIdx.x & 63) == 0) { sl[wid] = lf; sn[wid] = ns; }
  __syncthreads();
  if (threadIdx.x == 0)
    bsums[blockIdx.x] = make_float2(sl[0] + sl[1] + sl[2] + sl[3],
                                    sn[0] + sn[1] + sn[2] + sn[3]);
}

__global__ __launch_bounds__(64) void k3b(const float2* __restrict__ bsums,
                                          float* __restrict__ out)
{
  if (threadIdx.x == 0) {
    float L = 0.f, C = 0.f;
    for (int b = 0; b < 8; ++b) { L += bsums[b].x; C += bsums[b].y; }
    out[0] = L / fmaxf(C, 1.0f);
  }
}

// ---------------------------------------------------------------------------
extern "C" void kernel_launch(void* const* d_in, const int* in_sizes, int n_in,
                              void* d_out, int out_size, void* d_ws, size_t ws_size,
                              hipStream_t stream) {
  const float* E   = (const float*)d_in[0];
  const int*   tid = (const int*)d_in[1];
  const int*   msk = (const int*)d_in[2];
  const float* Wmu = (const float*)d_in[3];
  const float* bmu = (const float*)d_in[4];
  const float* Wsg = (const float*)d_in[5];
  const float* bsg = (const float*)d_in[6];

  unsigned char* w = (unsigned char*)d_ws;
  unsigned short* Ehi  = (unsigned short*)w;  w += (size_t)NROWS * HDIM * 2;   // 3 MB
  unsigned short* Elo  = (unsigned short*)w;  w += (size_t)NROWS * HDIM * 2;   // 3 MB
  unsigned short* Wthi = (unsigned short*)w;  w += (size_t)256 * HDIM * 2;     // 384 KB
  unsigned short* Wtlo = (unsigned short*)w;  w += (size_t)256 * HDIM * 2;     // 384 KB
  unsigned short* Fhi  = (unsigned short*)w;  w += (size_t)NROWS * FEAT * 2;   // 2 MB
  unsigned short* Flo  = (unsigned short*)w;  w += (size_t)NROWS * FEAT * 2;   // 2 MB
  float* Cpart         = (float*)w;           w += (size_t)4 * NROWS * 256 * 4; // 8 MB
  float* qv            = (float*)w;           w += (size_t)NROWS * 4;
  unsigned long long* tab = (unsigned long long*)w; w += (size_t)TSLOTS * 8;   // 64 KB
  int* rowflag         = (int*)w;             w += (size_t)NROWS * 4;
  int* dupcnt          = (int*)w;             w += 256;
  float2* bsums        = (float2*)w;          w += 256;
  int2* duplist        = (int2*)w;            w += (size_t)DCAP * 8;
  float4* partials     = (float4*)w;          w += (size_t)64 * NROWS * 16;    // 2 MB

  k0_prep<<<873, 256, 0, stream>>>(E, Wmu, Wsg, Ehi, Elo, Wthi, Wtlo,
                                   tab, rowflag, dupcnt);
  k1m<<<256, 256, 0, stream>>>(Ehi, Elo, Wthi, Wtlo, Cpart);
  k1e<<<512, 256, 0, stream>>>(Cpart, bmu, bsg, Fhi, Flo, qv,
                               tab, rowflag, dupcnt, duplist);
  k2_mfma<<<dim3(16, 16), 512, 0, stream>>>(Fhi, Flo, qv, tid, msk, rowflag,
                                            dupcnt, duplist, partials);
  k3a<<<8, 256, 0, stream>>>(partials, bsums);
  k3b<<<1, 64, 0, stream>>>(bsums, (float*)d_out);
}